// Round 8
// baseline (309.064 us; speedup 1.0000x reference)
//
#include <hip/hip_runtime.h>
#include <math.h>

using bf16x8  = __attribute__((ext_vector_type(8))) __bf16;
using floatx4 = __attribute__((ext_vector_type(4))) float;
using ushortx8 = __attribute__((ext_vector_type(8))) unsigned short;
typedef unsigned short u16;

__device__ __forceinline__ float bf2f(u16 u) {
  unsigned int x = ((unsigned int)u) << 16;
  return __builtin_bit_cast(float, x);
}
__device__ __forceinline__ u16 f2bf(float f) {
  unsigned int x = __builtin_bit_cast(unsigned int, f);
  x += 0x7FFFu + ((x >> 16) & 1u);   // round-to-nearest-even
  return (u16)(x >> 16);
}
__device__ __forceinline__ float fexp2(float x) { return __builtin_amdgcn_exp2f(x); }

// ---------------- x: fp32 -> bf16 ----------------
__global__ __launch_bounds__(256) void cvt_kernel(const float* __restrict__ x, u16* __restrict__ xb) {
  int g = (blockIdx.x * 256 + threadIdx.x) * 8;
  float4 a = *(const float4*)(x + g);
  float4 b = *(const float4*)(x + g + 4);
  ushortx8 o;
  o[0] = f2bf(a.x); o[1] = f2bf(a.y); o[2] = f2bf(a.z); o[3] = f2bf(a.w);
  o[4] = f2bf(b.x); o[5] = f2bf(b.y); o[6] = f2bf(b.z); o[7] = f2bf(b.w);
  *(ushortx8*)(xb + g) = o;
}

// ---------------- weight scale: sum |W| ----------------
__global__ __launch_bounds__(256) void absum_kernel(const float* W0, const float* W1,
                                                    const float* W2, const float* W3,
                                                    float* partials) {
  const float* W = (blockIdx.y == 0) ? W0 : (blockIdx.y == 1) ? W1 : (blockIdx.y == 2) ? W2 : W3;
  int tid = threadIdx.x;
  int base = blockIdx.x * 16384 + tid;
  float s = 0.f;
#pragma unroll
  for (int i = 0; i < 64; ++i) s += fabsf(W[base + i * 256]);
  __shared__ float red[256];
  red[tid] = s;
  __syncthreads();
  for (int off = 128; off > 0; off >>= 1) {
    if (tid < off) red[tid] += red[tid + off];
    __syncthreads();
  }
  if (tid == 0) partials[blockIdx.y * 64 + blockIdx.x] = red[0];
}

__global__ void scales_kernel(const float* partials, float* scales) {
  int w = threadIdx.x;
  if (w < 4) {
    float s = 0.f;
    for (int i = 0; i < 64; ++i) s += partials[w * 64 + i];
    scales[w] = s * (1.f / 1048576.f);
  }
}

// ---------------- ternary quantize ----------------
__global__ __launch_bounds__(256) void quant_kernel(const float* W0, const float* W1,
                                                    const float* W2, const float* W3,
                                                    const float* scales, u16* Wt) {
  int w = blockIdx.y;
  const float* W = (w == 0) ? W0 : (w == 1) ? W1 : (w == 2) ? W2 : W3;
  u16* O = Wt + (size_t)w * (1u << 20);
  float s = scales[w] + 1e-8f;
  int e = blockIdx.x * 256 + threadIdx.x;
  float t = W[e] / s;
  t = fminf(fmaxf(t, -1.f), 1.f);
  O[e] = f2bf(rintf(t));
}

// ---------------- fused QKV GEMM (round-6 known-good): 128x64 tile, glds staging ----------------
__global__ __launch_bounds__(256) void gemm_qkv(const u16* __restrict__ A, const u16* __restrict__ Wt,
                                                u16* __restrict__ QKV, const float* __restrict__ scales) {
  const int K = 1024;
  __shared__ __align__(16) u16 As[128][64];
  __shared__ __align__(16) u16 Bs[64][64];
  int tid = threadIdx.x;
  int wave = tid >> 6, lane = tid & 63;
  int quad = lane >> 4, l16 = lane & 15;
  int bm = blockIdx.x * 128;
  int bnc = blockIdx.y * 64;
  int mat = bnc >> 10, bn = bnc & 1023;
  int wm = (wave >> 1) * 64, wn = (wave & 1) * 32;
  floatx4 acc[4][2] = {};
  const u16* ga = A  + (size_t)(bm + wave * 32 + (lane >> 3)) * K + (lane & 7) * 8;
  const u16* gb = Wt + (size_t)(bnc + wave * 16 + (lane >> 3)) * K + (lane & 7) * 8;
  for (int k0 = 0; k0 < K; k0 += 64) {
    __syncthreads();
#pragma unroll
    for (int i = 0; i < 4; ++i)
      __builtin_amdgcn_global_load_lds(
          (const __attribute__((address_space(1))) void*)(ga + (size_t)i * 8 * K + k0),
          (__attribute__((address_space(3))) void*)(&As[wave * 32 + i * 8][0]), 16, 0, 0);
#pragma unroll
    for (int i = 0; i < 2; ++i)
      __builtin_amdgcn_global_load_lds(
          (const __attribute__((address_space(1))) void*)(gb + (size_t)i * 8 * K + k0),
          (__attribute__((address_space(3))) void*)(&Bs[wave * 16 + i * 8][0]), 16, 0, 0);
    __syncthreads();
#pragma unroll
    for (int kk = 0; kk < 64; kk += 32) {
      bf16x8 a[4], b[2];
#pragma unroll
      for (int i = 0; i < 4; ++i)
        a[i] = __builtin_bit_cast(bf16x8, *(const ushortx8*)&As[wm + i * 16 + l16][kk + quad * 8]);
#pragma unroll
      for (int j = 0; j < 2; ++j)
        b[j] = __builtin_bit_cast(bf16x8, *(const ushortx8*)&Bs[wn + j * 16 + l16][kk + quad * 8]);
#pragma unroll
      for (int i = 0; i < 4; ++i)
#pragma unroll
        for (int j = 0; j < 2; ++j)
          acc[i][j] = __builtin_amdgcn_mfma_f32_16x16x32_bf16(a[i], b[j], acc[i][j], 0, 0, 0);
    }
  }
  float sc = scales[mat];
  u16* out = QKV + (size_t)mat * (4u << 20);
#pragma unroll
  for (int i = 0; i < 4; ++i)
#pragma unroll
    for (int j = 0; j < 2; ++j)
#pragma unroll
      for (int rg = 0; rg < 4; ++rg) {
        int row = bm + wm + i * 16 + quad * 4 + rg;
        int col = bn + wn + j * 16 + l16;
        out[(size_t)row * 1024 + col] = f2bf(acc[i][j][rg] * sc);
      }
}

// ---------------- output projection GEMM (round-6 known-good, fp32 out) ----------------
__global__ __launch_bounds__(256) void gemm_out(const u16* __restrict__ A, const u16* __restrict__ B,
                                                float* __restrict__ C, const float* __restrict__ scale_ptr) {
  const int K = 1024, N = 1024;
  __shared__ __align__(16) u16 As[128][64];
  __shared__ __align__(16) u16 Bs[64][64];
  int tid = threadIdx.x;
  int wave = tid >> 6, lane = tid & 63;
  int quad = lane >> 4, l16 = lane & 15;
  int bm = blockIdx.x * 128, bn = blockIdx.y * 64;
  int wm = (wave >> 1) * 64, wn = (wave & 1) * 32;
  floatx4 acc[4][2] = {};
  const u16* ga = A + (size_t)(bm + wave * 32 + (lane >> 3)) * K + (lane & 7) * 8;
  const u16* gb = B + (size_t)(bn + wave * 16 + (lane >> 3)) * K + (lane & 7) * 8;
  for (int k0 = 0; k0 < K; k0 += 64) {
    __syncthreads();
#pragma unroll
    for (int i = 0; i < 4; ++i)
      __builtin_amdgcn_global_load_lds(
          (const __attribute__((address_space(1))) void*)(ga + (size_t)i * 8 * K + k0),
          (__attribute__((address_space(3))) void*)(&As[wave * 32 + i * 8][0]), 16, 0, 0);
#pragma unroll
    for (int i = 0; i < 2; ++i)
      __builtin_amdgcn_global_load_lds(
          (const __attribute__((address_space(1))) void*)(gb + (size_t)i * 8 * K + k0),
          (__attribute__((address_space(3))) void*)(&Bs[wave * 16 + i * 8][0]), 16, 0, 0);
    __syncthreads();
#pragma unroll
    for (int kk = 0; kk < 64; kk += 32) {
      bf16x8 a[4], b[2];
#pragma unroll
      for (int i = 0; i < 4; ++i)
        a[i] = __builtin_bit_cast(bf16x8, *(const ushortx8*)&As[wm + i * 16 + l16][kk + quad * 8]);
#pragma unroll
      for (int j = 0; j < 2; ++j)
        b[j] = __builtin_bit_cast(bf16x8, *(const ushortx8*)&Bs[wn + j * 16 + l16][kk + quad * 8]);
#pragma unroll
      for (int i = 0; i < 4; ++i)
#pragma unroll
        for (int j = 0; j < 2; ++j)
          acc[i][j] = __builtin_amdgcn_mfma_f32_16x16x32_bf16(a[i], b[j], acc[i][j], 0, 0, 0);
    }
  }
  float sc = scale_ptr[0];
#pragma unroll
  for (int i = 0; i < 4; ++i)
#pragma unroll
    for (int j = 0; j < 2; ++j)
#pragma unroll
      for (int rg = 0; rg < 4; ++rg) {
        int row = bm + wm + i * 16 + quad * 4 + rg;
        int col = bn + wn + j * 16 + l16;
        C[(size_t)row * N + col] = acc[i][j][rg] * sc;
      }
}

// ---------------- RoPE; folds (1/sqrt(64))*log2(e) into q ----------------
__global__ __launch_bounds__(256) void rope_kernel(u16* q, u16* k) {
  const float QS = 0.125f * 1.4426950408889634f;
  int gid = blockIdx.x * 256 + threadIdx.x;
  int i = gid & 31;
  int h = (gid >> 5) & 15;
  int bt = gid >> 9;
  int t = bt & 2047;
  float inv = exp2f(-(float)i * (13.287712379549449f / 32.f));
  float ang = (float)t * inv;
  float s = __sinf(ang), c = __cosf(ang);
  int row = bt * 1024 + h * 64;
  float q1 = bf2f(q[row + i]), q2 = bf2f(q[row + i + 32]);
  q[row + i]      = f2bf((q1 * c - q2 * s) * QS);
  q[row + i + 32] = f2bf((q2 * c + q1 * s) * QS);
  float k1 = bf2f(k[row + i]), k2 = bf2f(k[row + i + 32]);
  k[row + i]      = f2bf(k1 * c - k2 * s);
  k[row + i + 32] = f2bf(k2 * c + k1 * s);
}

// ---------------- V transpose: v[b][t][h*64+d] -> vt[b*16+h][d][t] ----------------
__global__ __launch_bounds__(256) void vtrans_kernel(const u16* __restrict__ v, u16* __restrict__ vt) {
  __shared__ u16 L[64][66];
  int bh = blockIdx.y, b = bh >> 4, h = bh & 15;
  int t0 = blockIdx.x * 64;
  int tid = threadIdx.x;
  int r = tid >> 2, c = (tid & 3) << 4;
  const u16* src = v + (size_t)(b * 2048 + t0 + r) * 1024 + h * 64 + c;
  *(ushortx8*)&L[r][c]     = *(const ushortx8*)src;
  *(ushortx8*)&L[r][c + 8] = *(const ushortx8*)(src + 8);
  __syncthreads();
  int d = tid >> 2, tc = (tid & 3) << 4;
  ushortx8 o0, o1;
#pragma unroll
  for (int j = 0; j < 8; ++j) { o0[j] = L[tc + j][d]; o1[j] = L[tc + 8 + j][d]; }
  u16* dst = vt + (size_t)(bh * 64 + d) * 2048 + t0 + tc;
  *(ushortx8*)dst       = o0;
  *(ushortx8*)(dst + 8) = o1;
}

// ---------------- causal flash attention v6: barrier-free ----------------
// Waves fully independent (32 q-rows each). K and pre-transposed V are loaded
// straight from global memory in MFMA fragment layout (no K/V LDS, no
// __syncthreads). LDS only for the same-wave P^T->A-frag roundtrip.
__global__ __launch_bounds__(256, 3) void attn_kernel(const u16* __restrict__ q, const u16* __restrict__ k,
                                                      const u16* __restrict__ vt, u16* __restrict__ y) {
  __shared__ __align__(16) u16 Ps[8][16][72];
  const int T = 2048, C = 1024;
  int tid = threadIdx.x;
  int wave = tid >> 6, lane = tid & 63;
  int quad = lane >> 4, l16 = lane & 15;
  int p = (int)gridDim.x - 1 - (int)blockIdx.x;  // heavy blocks first
  int b = blockIdx.y >> 4, h = blockIdx.y & 15;
  int wq0 = p * 128 + wave * 32;
  int dtile = wq0 >> 6;           // this wave's diagonal 64-key tile
  int nkt = dtile + 1;

  bf16x8 bq[2][2];
#pragma unroll
  for (int qi = 0; qi < 2; ++qi) {
    const u16* gq = q + (size_t)(b * T + wq0 + qi * 16 + l16) * C + h * 64 + quad * 8;
    bq[qi][0] = __builtin_bit_cast(bf16x8, *(const ushortx8*)(gq));
    bq[qi][1] = __builtin_bit_cast(bf16x8, *(const ushortx8*)(gq + 32));
  }

  ushortx8 onesu;
#pragma unroll
  for (int j = 0; j < 8; ++j) onesu[j] = 0x3F80;  // bf16 1.0
  bf16x8 bones = __builtin_bit_cast(bf16x8, onesu);

  // fragment base pointers (per-lane)
  const u16* kfrag = k  + (size_t)(b * T + l16) * C + h * 64 + quad * 8;        // + key*C
  const u16* vfrag = vt + (size_t)(blockIdx.y * 64 + l16) * 2048 + quad * 8;    // + nt*16*2048 + t

  float mrun[2] = {-__builtin_inff(), -__builtin_inff()};
  floatx4 o[2][5] = {};  // [qi][0..3]=O tiles, [4]=row-sum l

  for (int kt = 0; kt < nkt; ++kt) {
    int kb = kt * 64;
    // S^T = K Q^T : lane holds S[q=l16][key = kb + nt*16 + quad*4 + rg], per qi
    floatx4 sacc[2][4] = {};
#pragma unroll
    for (int nt = 0; nt < 4; ++nt) {
      const u16* kp = kfrag + (size_t)(kb + nt * 16) * C;
      bf16x8 ak0 = __builtin_bit_cast(bf16x8, *(const ushortx8*)(kp));
      bf16x8 ak1 = __builtin_bit_cast(bf16x8, *(const ushortx8*)(kp + 32));
#pragma unroll
      for (int qi = 0; qi < 2; ++qi) {
        sacc[qi][nt] = __builtin_amdgcn_mfma_f32_16x16x32_bf16(ak0, bq[qi][0], sacc[qi][nt], 0, 0, 0);
        sacc[qi][nt] = __builtin_amdgcn_mfma_f32_16x16x32_bf16(ak1, bq[qi][1], sacc[qi][nt], 0, 0, 0);
      }
    }

    float alpha[2];
#pragma unroll
    for (int qi = 0; qi < 2; ++qi) {
      if (kt == dtile) {  // causal mask, diagonal tile only
        int qg = wq0 + qi * 16 + l16;
#pragma unroll
        for (int nt = 0; nt < 4; ++nt)
#pragma unroll
          for (int rg = 0; rg < 4; ++rg)
            if (kb + nt * 16 + quad * 4 + rg > qg) sacc[qi][nt][rg] = -__builtin_inff();
      }
      float mx = fmaxf(fmaxf(sacc[qi][0][0], sacc[qi][0][1]), fmaxf(sacc[qi][0][2], sacc[qi][0][3]));
#pragma unroll
      for (int nt = 1; nt < 4; ++nt)
        mx = fmaxf(mx, fmaxf(fmaxf(sacc[qi][nt][0], sacc[qi][nt][1]),
                             fmaxf(sacc[qi][nt][2], sacc[qi][nt][3])));
      mx = fmaxf(mx, __shfl_xor(mx, 16, 64));
      mx = fmaxf(mx, __shfl_xor(mx, 32, 64));
      mx = fmaxf(mx, mrun[qi]);
      alpha[qi] = fexp2(mrun[qi] - mx);
      mrun[qi] = mx;
#pragma unroll
      for (int nt = 0; nt < 4; ++nt) {
        unsigned lo = (unsigned)f2bf(fexp2(sacc[qi][nt][0] - mx)) |
                      ((unsigned)f2bf(fexp2(sacc[qi][nt][1] - mx)) << 16);
        unsigned hi = (unsigned)f2bf(fexp2(sacc[qi][nt][2] - mx)) |
                      ((unsigned)f2bf(fexp2(sacc[qi][nt][3] - mx)) << 16);
        *(uint2*)&Ps[wave * 2 + qi][l16][nt * 16 + quad * 4] = make_uint2(lo, hi);
      }
    }

    // rescale O rows (q = quad*4+rg) by that row's alpha
#pragma unroll
    for (int qi = 0; qi < 2; ++qi)
#pragma unroll
      for (int rg = 0; rg < 4; ++rg) {
        float ar = __shfl(alpha[qi], quad * 4 + rg, 64);
#pragma unroll
        for (int a = 0; a < 5; ++a) o[qi][a][rg] *= ar;
      }

    // P (A-frag, via same-wave LDS roundtrip) x V (B-frag direct from global)
    bf16x8 ap[2][2];
#pragma unroll
    for (int qi = 0; qi < 2; ++qi) {
      ap[qi][0] = __builtin_bit_cast(bf16x8, *(const ushortx8*)&Ps[wave * 2 + qi][l16][quad * 8]);
      ap[qi][1] = __builtin_bit_cast(bf16x8, *(const ushortx8*)&Ps[wave * 2 + qi][l16][32 + quad * 8]);
    }
#pragma unroll
    for (int nt = 0; nt < 4; ++nt) {
      const u16* vp = vfrag + (size_t)(nt * 16) * 2048 + kb;
      bf16x8 bv0 = __builtin_bit_cast(bf16x8, *(const ushortx8*)(vp));
      bf16x8 bv1 = __builtin_bit_cast(bf16x8, *(const ushortx8*)(vp + 32));
#pragma unroll
      for (int qi = 0; qi < 2; ++qi) {
        o[qi][nt] = __builtin_amdgcn_mfma_f32_16x16x32_bf16(ap[qi][0], bv0, o[qi][nt], 0, 0, 0);
        o[qi][nt] = __builtin_amdgcn_mfma_f32_16x16x32_bf16(ap[qi][1], bv1, o[qi][nt], 0, 0, 0);
      }
    }
#pragma unroll
    for (int qi = 0; qi < 2; ++qi) {
      o[qi][4] = __builtin_amdgcn_mfma_f32_16x16x32_bf16(ap[qi][0], bones, o[qi][4], 0, 0, 0);
      o[qi][4] = __builtin_amdgcn_mfma_f32_16x16x32_bf16(ap[qi][1], bones, o[qi][4], 0, 0, 0);
    }
  }

#pragma unroll
  for (int qi = 0; qi < 2; ++qi)
#pragma unroll
    for (int nt = 0; nt < 4; ++nt)
#pragma unroll
      for (int rg = 0; rg < 4; ++rg) {
        int qg = wq0 + qi * 16 + quad * 4 + rg;
        int col = h * 64 + nt * 16 + l16;
        y[(size_t)(b * T + qg) * C + col] = f2bf(o[qi][nt][rg] / o[qi][4][rg]);
      }
}

extern "C" void kernel_launch(void* const* d_in, const int* in_sizes, int n_in,
                              void* d_out, int out_size, void* d_ws, size_t ws_size,
                              hipStream_t stream) {
  const float* x  = (const float*)d_in[0];
  const float* Wq = (const float*)d_in[1];
  const float* Wk = (const float*)d_in[2];
  const float* Wv = (const float*)d_in[3];
  const float* Wo = (const float*)d_in[4];

  char* ws = (char*)d_ws;
  float* partials = (float*)ws;
  float* scales   = (float*)(ws + 1024);
  u16* Wt  = (u16*)(ws + 4096);                       // 4 x 1M bf16 ternary (Q,K,V,O stacked)
  u16* xb  = (u16*)(ws + 4096 + (size_t)(8u << 20));
  u16* qb  = xb + (4u << 20);                         // qb,kb,vb contiguous (QKV epilogue routing)
  u16* kb  = qb + (4u << 20);
  u16* vb  = kb + (4u << 20);
  u16* vtb = vb + (4u << 20);
  u16* yb  = vtb + (4u << 20);
  float* out = (float*)d_out;

  cvt_kernel<<<2048, 256, 0, stream>>>(x, xb);
  absum_kernel<<<dim3(64, 4), 256, 0, stream>>>(Wq, Wk, Wv, Wo, partials);
  scales_kernel<<<1, 64, 0, stream>>>(partials, scales);
  quant_kernel<<<dim3(4096, 4), 256, 0, stream>>>(Wq, Wk, Wv, Wo, scales, Wt);

  gemm_qkv<<<dim3(32, 48), 256, 0, stream>>>(xb, Wt, qb, scales);
  rope_kernel<<<8192, 256, 0, stream>>>(qb, kb);
  vtrans_kernel<<<dim3(32, 32), 256, 0, stream>>>(vb, vtb);
  attn_kernel<<<dim3(16, 32), 256, 0, stream>>>(qb, kb, vtb, yb);
  gemm_out<<<dim3(32, 16), 256, 0, stream>>>(yb, Wt + 3 * (1u << 20), out, scales + 3);
}

// Round 9
// 230.274 us; speedup vs baseline: 1.3422x; 1.3422x over previous
//
#include <hip/hip_runtime.h>
#include <math.h>

using bf16x8  = __attribute__((ext_vector_type(8))) __bf16;
using floatx4 = __attribute__((ext_vector_type(4))) float;
using ushortx8 = __attribute__((ext_vector_type(8))) unsigned short;
typedef unsigned short u16;

__device__ __forceinline__ float bf2f(u16 u) {
  unsigned int x = ((unsigned int)u) << 16;
  return __builtin_bit_cast(float, x);
}
__device__ __forceinline__ u16 f2bf(float f) {
  unsigned int x = __builtin_bit_cast(unsigned int, f);
  x += 0x7FFFu + ((x >> 16) & 1u);   // round-to-nearest-even
  return (u16)(x >> 16);
}
__device__ __forceinline__ float fexp2(float x) { return __builtin_amdgcn_exp2f(x); }

// ---------------- x: fp32 -> bf16 ----------------
__global__ __launch_bounds__(256) void cvt_kernel(const float* __restrict__ x, u16* __restrict__ xb) {
  int g = (blockIdx.x * 256 + threadIdx.x) * 8;
  float4 a = *(const float4*)(x + g);
  float4 b = *(const float4*)(x + g + 4);
  ushortx8 o;
  o[0] = f2bf(a.x); o[1] = f2bf(a.y); o[2] = f2bf(a.z); o[3] = f2bf(a.w);
  o[4] = f2bf(b.x); o[5] = f2bf(b.y); o[6] = f2bf(b.z); o[7] = f2bf(b.w);
  *(ushortx8*)(xb + g) = o;
}

// ---------------- weight scale: sum |W| ----------------
__global__ __launch_bounds__(256) void absum_kernel(const float* W0, const float* W1,
                                                    const float* W2, const float* W3,
                                                    float* partials) {
  const float* W = (blockIdx.y == 0) ? W0 : (blockIdx.y == 1) ? W1 : (blockIdx.y == 2) ? W2 : W3;
  int tid = threadIdx.x;
  int base = blockIdx.x * 16384 + tid;
  float s = 0.f;
#pragma unroll
  for (int i = 0; i < 64; ++i) s += fabsf(W[base + i * 256]);
  __shared__ float red[256];
  red[tid] = s;
  __syncthreads();
  for (int off = 128; off > 0; off >>= 1) {
    if (tid < off) red[tid] += red[tid + off];
    __syncthreads();
  }
  if (tid == 0) partials[blockIdx.y * 64 + blockIdx.x] = red[0];
}

__global__ void scales_kernel(const float* partials, float* scales) {
  int w = threadIdx.x;
  if (w < 4) {
    float s = 0.f;
    for (int i = 0; i < 64; ++i) s += partials[w * 64 + i];
    scales[w] = s * (1.f / 1048576.f);
  }
}

// ---------------- ternary quantize ----------------
__global__ __launch_bounds__(256) void quant_kernel(const float* W0, const float* W1,
                                                    const float* W2, const float* W3,
                                                    const float* scales, u16* Wt) {
  int w = blockIdx.y;
  const float* W = (w == 0) ? W0 : (w == 1) ? W1 : (w == 2) ? W2 : W3;
  u16* O = Wt + (size_t)w * (1u << 20);
  float s = scales[w] + 1e-8f;
  int e = blockIdx.x * 256 + threadIdx.x;
  float t = W[e] / s;
  t = fminf(fmaxf(t, -1.f), 1.f);
  O[e] = f2bf(rintf(t));
}

// ---------------- fused QKV GEMM: 128x64 tile, glds staging ----------------
__global__ __launch_bounds__(256) void gemm_qkv(const u16* __restrict__ A, const u16* __restrict__ Wt,
                                                u16* __restrict__ QKV, const float* __restrict__ scales) {
  const int K = 1024;
  __shared__ __align__(16) u16 As[128][64];
  __shared__ __align__(16) u16 Bs[64][64];
  int tid = threadIdx.x;
  int wave = tid >> 6, lane = tid & 63;
  int quad = lane >> 4, l16 = lane & 15;
  int bm = blockIdx.x * 128;
  int bnc = blockIdx.y * 64;
  int mat = bnc >> 10, bn = bnc & 1023;
  int wm = (wave >> 1) * 64, wn = (wave & 1) * 32;
  floatx4 acc[4][2] = {};
  const u16* ga = A  + (size_t)(bm + wave * 32 + (lane >> 3)) * K + (lane & 7) * 8;
  const u16* gb = Wt + (size_t)(bnc + wave * 16 + (lane >> 3)) * K + (lane & 7) * 8;
  for (int k0 = 0; k0 < K; k0 += 64) {
    __syncthreads();
#pragma unroll
    for (int i = 0; i < 4; ++i)
      __builtin_amdgcn_global_load_lds(
          (const __attribute__((address_space(1))) void*)(ga + (size_t)i * 8 * K + k0),
          (__attribute__((address_space(3))) void*)(&As[wave * 32 + i * 8][0]), 16, 0, 0);
#pragma unroll
    for (int i = 0; i < 2; ++i)
      __builtin_amdgcn_global_load_lds(
          (const __attribute__((address_space(1))) void*)(gb + (size_t)i * 8 * K + k0),
          (__attribute__((address_space(3))) void*)(&Bs[wave * 16 + i * 8][0]), 16, 0, 0);
    __syncthreads();
#pragma unroll
    for (int kk = 0; kk < 64; kk += 32) {
      bf16x8 a[4], b[2];
#pragma unroll
      for (int i = 0; i < 4; ++i)
        a[i] = __builtin_bit_cast(bf16x8, *(const ushortx8*)&As[wm + i * 16 + l16][kk + quad * 8]);
#pragma unroll
      for (int j = 0; j < 2; ++j)
        b[j] = __builtin_bit_cast(bf16x8, *(const ushortx8*)&Bs[wn + j * 16 + l16][kk + quad * 8]);
#pragma unroll
      for (int i = 0; i < 4; ++i)
#pragma unroll
        for (int j = 0; j < 2; ++j)
          acc[i][j] = __builtin_amdgcn_mfma_f32_16x16x32_bf16(a[i], b[j], acc[i][j], 0, 0, 0);
    }
  }
  float sc = scales[mat];
  u16* out = QKV + (size_t)mat * (4u << 20);
#pragma unroll
  for (int i = 0; i < 4; ++i)
#pragma unroll
    for (int j = 0; j < 2; ++j)
#pragma unroll
      for (int rg = 0; rg < 4; ++rg) {
        int row = bm + wm + i * 16 + quad * 4 + rg;
        int col = bn + wn + j * 16 + l16;
        out[(size_t)row * 1024 + col] = f2bf(acc[i][j][rg] * sc);
      }
}

// ---------------- output projection GEMM (fp32 out) ----------------
__global__ __launch_bounds__(256) void gemm_out(const u16* __restrict__ A, const u16* __restrict__ B,
                                                float* __restrict__ C, const float* __restrict__ scale_ptr) {
  const int K = 1024, N = 1024;
  __shared__ __align__(16) u16 As[128][64];
  __shared__ __align__(16) u16 Bs[64][64];
  int tid = threadIdx.x;
  int wave = tid >> 6, lane = tid & 63;
  int quad = lane >> 4, l16 = lane & 15;
  int bm = blockIdx.x * 128, bn = blockIdx.y * 64;
  int wm = (wave >> 1) * 64, wn = (wave & 1) * 32;
  floatx4 acc[4][2] = {};
  const u16* ga = A + (size_t)(bm + wave * 32 + (lane >> 3)) * K + (lane & 7) * 8;
  const u16* gb = B + (size_t)(bn + wave * 16 + (lane >> 3)) * K + (lane & 7) * 8;
  for (int k0 = 0; k0 < K; k0 += 64) {
    __syncthreads();
#pragma unroll
    for (int i = 0; i < 4; ++i)
      __builtin_amdgcn_global_load_lds(
          (const __attribute__((address_space(1))) void*)(ga + (size_t)i * 8 * K + k0),
          (__attribute__((address_space(3))) void*)(&As[wave * 32 + i * 8][0]), 16, 0, 0);
#pragma unroll
    for (int i = 0; i < 2; ++i)
      __builtin_amdgcn_global_load_lds(
          (const __attribute__((address_space(1))) void*)(gb + (size_t)i * 8 * K + k0),
          (__attribute__((address_space(3))) void*)(&Bs[wave * 16 + i * 8][0]), 16, 0, 0);
    __syncthreads();
#pragma unroll
    for (int kk = 0; kk < 64; kk += 32) {
      bf16x8 a[4], b[2];
#pragma unroll
      for (int i = 0; i < 4; ++i)
        a[i] = __builtin_bit_cast(bf16x8, *(const ushortx8*)&As[wm + i * 16 + l16][kk + quad * 8]);
#pragma unroll
      for (int j = 0; j < 2; ++j)
        b[j] = __builtin_bit_cast(bf16x8, *(const ushortx8*)&Bs[wn + j * 16 + l16][kk + quad * 8]);
#pragma unroll
      for (int i = 0; i < 4; ++i)
#pragma unroll
        for (int j = 0; j < 2; ++j)
          acc[i][j] = __builtin_amdgcn_mfma_f32_16x16x32_bf16(a[i], b[j], acc[i][j], 0, 0, 0);
    }
  }
  float sc = scale_ptr[0];
#pragma unroll
  for (int i = 0; i < 4; ++i)
#pragma unroll
    for (int j = 0; j < 2; ++j)
#pragma unroll
      for (int rg = 0; rg < 4; ++rg) {
        int row = bm + wm + i * 16 + quad * 4 + rg;
        int col = bn + wn + j * 16 + l16;
        C[(size_t)row * N + col] = acc[i][j][rg] * sc;
      }
}

// ---------------- RoPE; folds (1/sqrt(64))*log2(e) into q ----------------
__global__ __launch_bounds__(256) void rope_kernel(u16* q, u16* k) {
  const float QS = 0.125f * 1.4426950408889634f;
  int gid = blockIdx.x * 256 + threadIdx.x;
  int i = gid & 31;
  int h = (gid >> 5) & 15;
  int bt = gid >> 9;
  int t = bt & 2047;
  float inv = exp2f(-(float)i * (13.287712379549449f / 32.f));
  float ang = (float)t * inv;
  float s = __sinf(ang), c = __cosf(ang);
  int row = bt * 1024 + h * 64;
  float q1 = bf2f(q[row + i]), q2 = bf2f(q[row + i + 32]);
  q[row + i]      = f2bf((q1 * c - q2 * s) * QS);
  q[row + i + 32] = f2bf((q2 * c + q1 * s) * QS);
  float k1 = bf2f(k[row + i]), k2 = bf2f(k[row + i + 32]);
  k[row + i]      = f2bf(k1 * c - k2 * s);
  k[row + i + 32] = f2bf(k2 * c + k1 * s);
}

// ---------------- V transpose: v[b][t][h*64+d] -> vt[b*16+h][d][t] ----------------
__global__ __launch_bounds__(256) void vtrans_kernel(const u16* __restrict__ v, u16* __restrict__ vt) {
  __shared__ u16 L[64][66];
  int bh = blockIdx.y, b = bh >> 4, h = bh & 15;
  int t0 = blockIdx.x * 64;
  int tid = threadIdx.x;
  int r = tid >> 2, c = (tid & 3) << 4;
  const u16* src = v + (size_t)(b * 2048 + t0 + r) * 1024 + h * 64 + c;
  *(ushortx8*)&L[r][c]     = *(const ushortx8*)src;
  *(ushortx8*)&L[r][c + 8] = *(const ushortx8*)(src + 8);
  __syncthreads();
  int d = tid >> 2, tc = (tid & 3) << 4;
  ushortx8 o0, o1;
#pragma unroll
  for (int j = 0; j < 8; ++j) { o0[j] = L[tc + j][d]; o1[j] = L[tc + 8 + j][d]; }
  u16* dst = vt + (size_t)(bh * 64 + d) * 2048 + t0 + tc;
  *(ushortx8*)dst       = o0;
  *(ushortx8*)(dst + 8) = o1;
}

// ---------------- causal flash attention v7: balanced strip pairs ----------------
// 32 strips of 64 q-rows; block p processes strips p AND 31-p -> every block does
// exactly 33 qi-tiles (perfect balance, no tail). LDS-staged dbuf K/V (1 barrier
// per tile), per-lane softmax on S^T, l via P*ones MFMA. Group A (strip p) goes
// inactive for kt > p (wave-uniform branch); group B (strip 31-p) runs all tiles.
__global__ __launch_bounds__(256, 2) void attn_kernel(const u16* __restrict__ q, const u16* __restrict__ k,
                                                      const u16* __restrict__ vt, u16* __restrict__ y) {
  __shared__ __align__(16) u16 Ks[2][64][72];
  __shared__ __align__(16) u16 Vt[2][64][72];
  __shared__ __align__(16) u16 Ps[8][16][72];
  const int T = 2048, C = 1024;
  int tid = threadIdx.x;
  int wave = tid >> 6, lane = tid & 63;
  int quad = lane >> 4, l16 = lane & 15;
  int p = blockIdx.x;                       // 0..15 -> strips p and 31-p
  int b = blockIdx.y >> 4, h = blockIdx.y & 15;
  int wq[2];
  wq[0] = p * 64 + wave * 16;               // group A
  wq[1] = (31 - p) * 64 + wave * 16;        // group B
  int dt[2] = {p, 31 - p};                  // diagonal 64-key tile per group
  int nkt = 32 - p;                         // tiles 0..31-p

  bf16x8 bq[2][2];
#pragma unroll
  for (int g = 0; g < 2; ++g) {
    const u16* gq = q + (size_t)(b * T + wq[g] + l16) * C + h * 64 + quad * 8;
    bq[g][0] = __builtin_bit_cast(bf16x8, *(const ushortx8*)(gq));
    bq[g][1] = __builtin_bit_cast(bf16x8, *(const ushortx8*)(gq + 32));
  }

  ushortx8 onesu;
#pragma unroll
  for (int j = 0; j < 8; ++j) onesu[j] = 0x3F80;  // bf16 1.0
  bf16x8 bones = __builtin_bit_cast(bf16x8, onesu);

  // staging: thread covers srow = tid>>2 (0..63), two 16B chunks at sc16
  int srow = tid >> 2, sc16 = (tid & 3) << 4;
  const u16* kptr  = k  + (size_t)(b * T + srow) * C + h * 64 + sc16;
  const u16* vtptr = vt + (size_t)(blockIdx.y * 64 + srow) * 2048 + sc16;

  float mrun[2] = {-__builtin_inff(), -__builtin_inff()};
  floatx4 o[2][5] = {};  // [group][0..3]=O tiles, [4]=row-sum l

  ushortx8 kra = *(const ushortx8*)kptr;
  ushortx8 krb = *(const ushortx8*)(kptr + 8);
  ushortx8 vra = *(const ushortx8*)vtptr;
  ushortx8 vrb = *(const ushortx8*)(vtptr + 8);
  *(ushortx8*)&Ks[0][srow][sc16]     = kra;
  *(ushortx8*)&Ks[0][srow][sc16 + 8] = krb;
  *(ushortx8*)&Vt[0][srow][sc16]     = vra;
  *(ushortx8*)&Vt[0][srow][sc16 + 8] = vrb;
  __syncthreads();

  for (int kt = 0; kt < nkt; ++kt) {
    int cur = kt & 1;
    bool haveNext = (kt + 1) < nkt;
    if (haveNext) {
      kra = *(const ushortx8*)(kptr + (size_t)(kt + 1) * 64 * C);
      krb = *(const ushortx8*)(kptr + (size_t)(kt + 1) * 64 * C + 8);
      vra = *(const ushortx8*)(vtptr + (kt + 1) * 64);
      vrb = *(const ushortx8*)(vtptr + (kt + 1) * 64 + 8);
    }

    bool act[2] = {kt <= dt[0], true};

    // S^T = K Q^T : lane holds S[q=l16][key = kt*64 + nt*16 + quad*4 + rg]
    floatx4 sacc[2][4] = {};
#pragma unroll
    for (int nt = 0; nt < 4; ++nt) {
      bf16x8 ak0 = __builtin_bit_cast(bf16x8, *(const ushortx8*)&Ks[cur][nt * 16 + l16][quad * 8]);
      bf16x8 ak1 = __builtin_bit_cast(bf16x8, *(const ushortx8*)&Ks[cur][nt * 16 + l16][32 + quad * 8]);
#pragma unroll
      for (int g = 0; g < 2; ++g)
        if (act[g]) {
          sacc[g][nt] = __builtin_amdgcn_mfma_f32_16x16x32_bf16(ak0, bq[g][0], sacc[g][nt], 0, 0, 0);
          sacc[g][nt] = __builtin_amdgcn_mfma_f32_16x16x32_bf16(ak1, bq[g][1], sacc[g][nt], 0, 0, 0);
        }
    }

#pragma unroll
    for (int g = 0; g < 2; ++g)
      if (act[g]) {
        if (kt == dt[g]) {  // causal mask, this group's diagonal tile
          int qg = wq[g] + l16;
#pragma unroll
          for (int nt = 0; nt < 4; ++nt)
#pragma unroll
            for (int rg = 0; rg < 4; ++rg)
              if (kt * 64 + nt * 16 + quad * 4 + rg > qg) sacc[g][nt][rg] = -__builtin_inff();
        }
        float mx = fmaxf(fmaxf(sacc[g][0][0], sacc[g][0][1]), fmaxf(sacc[g][0][2], sacc[g][0][3]));
#pragma unroll
        for (int nt = 1; nt < 4; ++nt)
          mx = fmaxf(mx, fmaxf(fmaxf(sacc[g][nt][0], sacc[g][nt][1]),
                               fmaxf(sacc[g][nt][2], sacc[g][nt][3])));
        mx = fmaxf(mx, __shfl_xor(mx, 16, 64));
        mx = fmaxf(mx, __shfl_xor(mx, 32, 64));
        mx = fmaxf(mx, mrun[g]);
        float alpha = fexp2(mrun[g] - mx);
        mrun[g] = mx;
#pragma unroll
        for (int nt = 0; nt < 4; ++nt) {
          unsigned lo = (unsigned)f2bf(fexp2(sacc[g][nt][0] - mx)) |
                        ((unsigned)f2bf(fexp2(sacc[g][nt][1] - mx)) << 16);
          unsigned hi = (unsigned)f2bf(fexp2(sacc[g][nt][2] - mx)) |
                        ((unsigned)f2bf(fexp2(sacc[g][nt][3] - mx)) << 16);
          *(uint2*)&Ps[wave * 2 + g][l16][nt * 16 + quad * 4] = make_uint2(lo, hi);
        }
        // rescale O rows (q = quad*4+rg) by that row's alpha
#pragma unroll
        for (int rg = 0; rg < 4; ++rg) {
          float ar = __shfl(alpha, quad * 4 + rg, 64);
#pragma unroll
          for (int a = 0; a < 5; ++a) o[g][a][rg] *= ar;
        }
      }

    // P (A-frag via same-wave LDS roundtrip) x V (B-frag from LDS, shared across groups)
    bf16x8 ap[2][2];
#pragma unroll
    for (int g = 0; g < 2; ++g)
      if (act[g]) {
        ap[g][0] = __builtin_bit_cast(bf16x8, *(const ushortx8*)&Ps[wave * 2 + g][l16][quad * 8]);
        ap[g][1] = __builtin_bit_cast(bf16x8, *(const ushortx8*)&Ps[wave * 2 + g][l16][32 + quad * 8]);
      }
#pragma unroll
    for (int nt = 0; nt < 4; ++nt) {
      bf16x8 bv0 = __builtin_bit_cast(bf16x8, *(const ushortx8*)&Vt[cur][nt * 16 + l16][quad * 8]);
      bf16x8 bv1 = __builtin_bit_cast(bf16x8, *(const ushortx8*)&Vt[cur][nt * 16 + l16][32 + quad * 8]);
#pragma unroll
      for (int g = 0; g < 2; ++g)
        if (act[g]) {
          o[g][nt] = __builtin_amdgcn_mfma_f32_16x16x32_bf16(ap[g][0], bv0, o[g][nt], 0, 0, 0);
          o[g][nt] = __builtin_amdgcn_mfma_f32_16x16x32_bf16(ap[g][1], bv1, o[g][nt], 0, 0, 0);
        }
    }
#pragma unroll
    for (int g = 0; g < 2; ++g)
      if (act[g]) {
        o[g][4] = __builtin_amdgcn_mfma_f32_16x16x32_bf16(ap[g][0], bones, o[g][4], 0, 0, 0);
        o[g][4] = __builtin_amdgcn_mfma_f32_16x16x32_bf16(ap[g][1], bones, o[g][4], 0, 0, 0);
      }

    if (haveNext) {
      int nb = cur ^ 1;
      *(ushortx8*)&Ks[nb][srow][sc16]     = kra;
      *(ushortx8*)&Ks[nb][srow][sc16 + 8] = krb;
      *(ushortx8*)&Vt[nb][srow][sc16]     = vra;
      *(ushortx8*)&Vt[nb][srow][sc16 + 8] = vrb;
    }
    __syncthreads();  // single barrier per tile
  }

#pragma unroll
  for (int g = 0; g < 2; ++g)
#pragma unroll
    for (int nt = 0; nt < 4; ++nt)
#pragma unroll
      for (int rg = 0; rg < 4; ++rg) {
        int qg = wq[g] + quad * 4 + rg;
        int col = h * 64 + nt * 16 + l16;
        y[(size_t)(b * T + qg) * C + col] = f2bf(o[g][nt][rg] / o[g][4][rg]);
      }
}

extern "C" void kernel_launch(void* const* d_in, const int* in_sizes, int n_in,
                              void* d_out, int out_size, void* d_ws, size_t ws_size,
                              hipStream_t stream) {
  const float* x  = (const float*)d_in[0];
  const float* Wq = (const float*)d_in[1];
  const float* Wk = (const float*)d_in[2];
  const float* Wv = (const float*)d_in[3];
  const float* Wo = (const float*)d_in[4];

  char* ws = (char*)d_ws;
  float* partials = (float*)ws;
  float* scales   = (float*)(ws + 1024);
  u16* Wt  = (u16*)(ws + 4096);                       // 4 x 1M bf16 ternary (Q,K,V,O stacked)
  u16* xb  = (u16*)(ws + 4096 + (size_t)(8u << 20));
  u16* qb  = xb + (4u << 20);                         // qb,kb,vb contiguous (QKV epilogue routing)
  u16* kb  = qb + (4u << 20);
  u16* vb  = kb + (4u << 20);
  u16* vtb = vb + (4u << 20);
  u16* yb  = vtb + (4u << 20);
  float* out = (float*)d_out;

  cvt_kernel<<<2048, 256, 0, stream>>>(x, xb);
  absum_kernel<<<dim3(64, 4), 256, 0, stream>>>(Wq, Wk, Wv, Wo, partials);
  scales_kernel<<<1, 64, 0, stream>>>(partials, scales);
  quant_kernel<<<dim3(4096, 4), 256, 0, stream>>>(Wq, Wk, Wv, Wo, scales, Wt);

  gemm_qkv<<<dim3(32, 48), 256, 0, stream>>>(xb, Wt, qb, scales);
  rope_kernel<<<8192, 256, 0, stream>>>(qb, kb);
  vtrans_kernel<<<dim3(32, 32), 256, 0, stream>>>(vb, vtb);
  attn_kernel<<<dim3(16, 32), 256, 0, stream>>>(qb, kb, vtb, yb);
  gemm_out<<<dim3(32, 16), 256, 0, stream>>>(yb, Wt + 3 * (1u << 20), out, scales + 3);
}